// Round 2
// 371.016 us; speedup vs baseline: 1.7501x; 1.7501x over previous
//
#include <hip/hip_runtime.h>
#include <stdint.h>

// Problem constants
#define NB 8192
#define NE 16
#define ND 128
#define NU 256
#define NF 256
#define NG 4
#define NK 6
#define ITEMP_LOG2E 144.26950408889634f  // (1/0.01) * log2(e)

typedef short short4v __attribute__((ext_vector_type(4)));
typedef short short8v __attribute__((ext_vector_type(8)));
typedef float float4v __attribute__((ext_vector_type(4)));

__device__ __forceinline__ short f2bf(float x) {
  uint32_t u = __builtin_bit_cast(uint32_t, x);
  u += 0x7FFFu + ((u >> 16) & 1u);       // round-to-nearest-even
  return (short)(u >> 16);
}

// ---------------------------------------------------------------------------
// prep kernel (unchanged, known-good): blocks [0,256) pack expert_kernels
// fp32 -> bf16 in MFMA B-fragment order; blocks [256,512) compute gating ->
// dense weights wd[b,g,e]
// ---------------------------------------------------------------------------
__global__ __launch_bounds__(256) void prep_kernel(
    const float* __restrict__ ek,     // [E,D,U]
    const float* __restrict__ feat,   // [B,F]
    const float* __restrict__ gk,     // [G,F,E]
    const float* __restrict__ gbias,  // [G,E]
    const float* __restrict__ gw,     // [E]
    short* __restrict__ pb,           // packed B frags: 65536*8 bf16
    float* __restrict__ wd)           // [B,G,E] dense weights
{
  __shared__ float fsh[32 * 256];
  int bid = blockIdx.x, tid = threadIdx.x;
  if (bid < 256) {
    // pack: frag element (e,ks,ut,lane,j) = ek[e][ks*32+(lane>>4)*8+j][ut*16+(lane&15)]
    int gid = (bid << 8) | tid;              // [0, 65536)
    int lane = gid & 63, ut = (gid >> 6) & 15, ks = (gid >> 10) & 3, e = gid >> 12;
    int krow = ks * 32 + ((lane >> 4) * 8);
    int ucol = ut * 16 + (lane & 15);
    const float* src = ek + (size_t)(e * 128 + krow) * 256 + ucol;
    short8v v;
#pragma unroll
    for (int j = 0; j < 8; ++j) v[j] = f2bf(src[(size_t)j * 256]);
    *(short8v*)(pb + (size_t)gid * 8) = v;
  } else {
    int b0 = (bid - 256) * 32;               // 32 batch rows per block
    {
      const float4v* s = (const float4v*)(feat + (size_t)b0 * 256);
      float4v* d = (float4v*)fsh;
      for (int i = tid; i < 2048; i += 256) d[i] = __builtin_nontemporal_load(s + i);
    }
    __syncthreads();
    int w = tid >> 6, lane = tid & 63;
    int gate = lane >> 4, e = lane & 15;     // lane = (gate, expert)
    float gwv = gw[e];
    float bias = gbias[gate * 16 + e];
    float acc[8];
#pragma unroll
    for (int i = 0; i < 8; ++i) acc[i] = bias;
    const float* gkp = gk + (size_t)gate * (NF * NE) + e;
    for (int f = 0; f < NF; f += 4) {
      float g0 = gkp[(f + 0) * 16], g1 = gkp[(f + 1) * 16];
      float g2 = gkp[(f + 2) * 16], g3 = gkp[(f + 3) * 16];
#pragma unroll
      for (int i = 0; i < 8; ++i) {          // 8 b's per wave; fsh read is wave-uniform (broadcast)
        float4v fv = *(const float4v*)&fsh[(w * 8 + i) * 256 + f];
        acc[i] = fmaf(fv[0], g0, acc[i]);
        acc[i] = fmaf(fv[1], g1, acc[i]);
        acc[i] = fmaf(fv[2], g2, acc[i]);
        acc[i] = fmaf(fv[3], g3, acc[i]);
      }
    }
#pragma unroll 1
    for (int i = 0; i < 8; ++i) {
      int b = b0 + w * 8 + i;
      float v = acc[i] > 0.f ? acc[i] : 0.f;  // relu
      v *= gwv;                               // * global_weights
      // sharp softmax over 16 experts (within 16-lane group)
      float m = v;
#pragma unroll
      for (int off = 1; off < 16; off <<= 1) m = fmaxf(m, __shfl_xor(m, off, 16));
      float ex = exp2f((v - m) * ITEMP_LOG2E);
      float s = ex;
#pragma unroll
      for (int off = 1; off < 16; off <<= 1) s += __shfl_xor(s, off, 16);
      float p = ex / s;
      // iterative top-6 (max value, min-index tie-break = jax top_k order)
      float cur = p;
      float topv[NK]; int topi[NK];
#pragma unroll
      for (int r = 0; r < NK; ++r) {
        float mv = cur;
#pragma unroll
        for (int off = 1; off < 16; off <<= 1) mv = fmaxf(mv, __shfl_xor(mv, off, 16));
        int cand = (cur == mv) ? e : 16;
#pragma unroll
        for (int off = 1; off < 16; off <<= 1) cand = min(cand, __shfl_xor(cand, off, 16));
        topv[r] = mv; topi[r] = cand;
        if (e == cand) cur = -1.f;
      }
      // second sharp softmax over the 6 selected (topv[0] is the max)
      float wv[NK], wsum = 0.f;
#pragma unroll
      for (int r = 0; r < NK; ++r) {
        wv[r] = exp2f((topv[r] - topv[0]) * ITEMP_LOG2E);
        wsum += wv[r];
      }
      float inv = 1.f / wsum;
      float wdv = 0.f;
#pragma unroll
      for (int r = 0; r < NK; ++r) wdv = (topi[r] == e) ? wv[r] * inv : wdv;
      wd[(size_t)b * 64 + gate * 16 + e] = wdv;   // dense [B,G,E]
    }
  }
}

// ---------------------------------------------------------------------------
// main kernel v2: 256 blocks x 512 threads, 32 b-rows per block (halves the
// pb logical traffic to 256 MB and puts exactly 1 block on each CU so all
// waves/CUs walk the same pb stream together -> L1/L2 temporal sharing).
// eo stores go through a per-wave 2KB LDS transpose buffer so every global
// store instruction writes a full contiguous 1KB line (kills the 16B-chunk
// stride-64 partial-line writes that inflated WRITE_SIZE 2.8x and caused
// write-allocate fetch). concat stores are paired across t so the two 64B
// halves of each 128B line are issued back-to-back.
// ---------------------------------------------------------------------------
#define APITCH 2056  // shorts per A row: 2048 + 8 pad
#define WPITCH 64    // floats per wd row (reads are 16-lane broadcast: no conflict)

__global__ __launch_bounds__(512, 2) void moe_kernel(
    const float* __restrict__ x,   // [B, E*D]
    const float* __restrict__ eb,  // [E, U]
    const short* __restrict__ pb,  // packed bf16 B frags
    const float* __restrict__ wd,  // [B, G, E]
    float* __restrict__ out)       // concat [B,G*U] then eo [B,U,E]
{
  __shared__ __align__(16) short ash[32 * APITCH];  // 131584 B
  __shared__ __align__(16) float wsh[32 * WPITCH];  // 8192 B
  __shared__ __align__(16) float stg[8 * 512];      // 16384 B (2KB per wave)
  int bt = blockIdx.x, tid = threadIdx.x;
  // dense gating weights for this block's 32 b's
#pragma unroll
  for (int k = 0; k < 4; ++k) {
    int i = tid + k * 512;
    wsh[(i >> 6) * WPITCH + (i & 63)] = wd[(size_t)bt * 2048 + i];
  }
  // stage A tile (32 rows x 2048) fp32 -> bf16 LDS, coalesced nt float4 reads
  {
    const float4v* s = (const float4v*)(x + (size_t)bt * 32 * 2048);
#pragma unroll
    for (int it = 0; it < 32; ++it) {
      int idx = tid + it * 512;
      int row = idx >> 9;            // / 512 f4-per-row
      int colf = (idx & 511) << 2;
      float4v v = __builtin_nontemporal_load(s + idx);
      short4v sv;
      sv[0] = f2bf(v[0]); sv[1] = f2bf(v[1]); sv[2] = f2bf(v[2]); sv[3] = f2bf(v[3]);
      *(short4v*)&ash[row * APITCH + colf] = sv;
    }
  }
  __syncthreads();

  int w = tid >> 6, lane = tid & 63;
  int btile = w >> 2, utq = w & 3;       // 8 waves = 2 b-tiles x 4 ut-quads
  int q = lane >> 4, col = lane & 15;    // C/D frag: row=q*4+r, col=lane&15
  int am = lane & 15;                    // A frag: m = lane&15
  float* outcat = out;
  float* outeo = out + (size_t)NB * NG * NU;
  const short8v* pbv = (const short8v*)pb;
  float* ws = stg + w * 512;             // this wave's 2KB staging slice
  size_t bb = (size_t)bt * 32 + btile * 16;
  int arow = (btile * 16 + am) * APITCH;
  int wrow = (btile * 16 + q * 4) * WPITCH;

  float csave[4][4];                     // concat values from even t, flushed at odd t

#pragma unroll 2
  for (int t = 0; t < 4; ++t) {
    int ut = utq * 4 + t;               // wave owns u_tiles [4*utq, 4*utq+4)
    float4v acc[16];
    float4v zero = {0.f, 0.f, 0.f, 0.f};
#pragma unroll
    for (int e = 0; e < 16; ++e) acc[e] = zero;
#pragma unroll
    for (int e = 0; e < 16; ++e) {
#pragma unroll
      for (int ks = 0; ks < 4; ++ks) {
        short8v a = *(const short8v*)&ash[arow + e * 128 + ks * 32 + q * 8];
        short8v b = pbv[((e * 4 + ks) * 16 + ut) * 64 + lane];
        acc[e] = __builtin_amdgcn_mfma_f32_16x16x32_bf16(a, b, acc[e], 0, 0, 0);
      }
    }
    // bias + leaky_relu
    float v[16][4];
#pragma unroll
    for (int e = 0; e < 16; ++e) {
      float bv = eb[e * 256 + ut * 16 + col];
#pragma unroll
      for (int r = 0; r < 4; ++r) {
        float z = acc[e][r] + bv;
        v[e][r] = z > 0.f ? z : 0.2f * z;
      }
    }
    // eo writes via LDS transpose: each flush instruction stores a full
    // contiguous 1KB (b,ut) region [16 u][16 e].
    // staging layout: [half][col][e] floats; e-chunk XOR-swizzled by col&3
    // to spread LDS write banks (<=4-way, ~free); flush reads are linear.
#pragma unroll
    for (int r = 0; r < 4; ++r) {
#pragma unroll
      for (int round = 0; round < 2; ++round) {
        if ((q >> 1) == round) {
          float* base = ws + (q & 1) * 256 + col * 16;
#pragma unroll
          for (int c = 0; c < 4; ++c) {
            float4v o = {v[4 * c + 0][r], v[4 * c + 1][r], v[4 * c + 2][r], v[4 * c + 3][r]};
            *(float4v*)(base + ((c ^ (col & 3)) * 4)) = o;
          }
        }
        __builtin_amdgcn_wave_barrier();   // compiler fence: write -> read (wave-synchronous LDS)
#pragma unroll
        for (int h = 0; h < 2; ++h) {
          size_t b = bb + (size_t)((round * 2 + h) * 4 + r);
          float4v val = *(const float4v*)(ws + h * 256 + lane * 4);  // linear, conflict-free
          int cc = (lane & 3) ^ ((lane >> 2) & 3);  // undo write swizzle in dst addr
          float* dst = outeo + b * 4096 + (size_t)ut * 256 + (lane >> 2) * 16 + cc * 4;
          __builtin_nontemporal_store(val, (float4v*)dst);
        }
        __builtin_amdgcn_wave_barrier();   // compiler fence: read -> next round's write
      }
    }
    // dense combine: out[b,g,u] = sum_e wd[b,g,e] * eo[b,u,e]
    // pair stores across (t-1,t): adjacent 64B halves of one 128B line.
#pragma unroll
    for (int r = 0; r < 4; ++r) {
      size_t b = bb + (size_t)(q * 4 + r);
#pragma unroll
      for (int g = 0; g < 4; ++g) {
        float sacc = 0.f;
#pragma unroll
        for (int ec = 0; ec < 16; ec += 4) {
          float4v wv = *(const float4v*)&wsh[wrow + r * WPITCH + g * 16 + ec];
          sacc = fmaf(wv[0], v[ec][r], sacc);
          sacc = fmaf(wv[1], v[ec + 1][r], sacc);
          sacc = fmaf(wv[2], v[ec + 2][r], sacc);
          sacc = fmaf(wv[3], v[ec + 3][r], sacc);
        }
        if ((t & 1) == 0) {
          csave[r][g] = sacc;
        } else {
          float* cb = outcat + b * 1024 + g * 256 + (ut - 1) * 16 + col;
          __builtin_nontemporal_store(csave[r][g], cb);
          __builtin_nontemporal_store(sacc, cb + 16);
        }
      }
    }
  }
}

extern "C" void kernel_launch(void* const* d_in, const int* in_sizes, int n_in,
                              void* d_out, int out_size, void* d_ws, size_t ws_size,
                              hipStream_t stream) {
  const float* x     = (const float*)d_in[0];  // [B, E*D]
  const float* feat  = (const float*)d_in[1];  // [B, F]
  const float* ek    = (const float*)d_in[2];  // [E, D, U]
  const float* eb    = (const float*)d_in[3];  // [E, U]
  const float* gk    = (const float*)d_in[4];  // [G, F, E]
  const float* gbias = (const float*)d_in[5];  // [G, E]
  const float* gw    = (const float*)d_in[6];  // [E]
  float* out = (float*)d_out;
  // workspace: [0, 2MB) dense gating weights, [2MB, 3MB) packed bf16 B frags
  float* wd  = (float*)d_ws;
  short* pbf = (short*)((char*)d_ws + (size_t)NB * NG * NE * 4);

  prep_kernel<<<512, 256, 0, stream>>>(ek, feat, gk, gbias, gw, pbf, wd);
  moe_kernel<<<256, 512, 0, stream>>>(x, eb, pbf, wd, out);
}

// Round 3
// 325.280 us; speedup vs baseline: 1.9961x; 1.1406x over previous
//
#include <hip/hip_runtime.h>
#include <stdint.h>

// Problem constants
#define NB 8192
#define NE 16
#define ND 128
#define NU 256
#define NF 256
#define NG 4
#define NK 6
#define ITEMP_LOG2E 144.26950408889634f  // (1/0.01) * log2(e)

typedef short short4v __attribute__((ext_vector_type(4)));
typedef short short8v __attribute__((ext_vector_type(8)));
typedef float float4v __attribute__((ext_vector_type(4)));

__device__ __forceinline__ short f2bf(float x) {
  uint32_t u = __builtin_bit_cast(uint32_t, x);
  u += 0x7FFFu + ((u >> 16) & 1u);       // round-to-nearest-even
  return (short)(u >> 16);
}

// ---------------------------------------------------------------------------
// prep kernel: pack expert_kernels fp32 -> bf16 in MFMA B-fragment order.
// (gating moved into moe_kernel; wd HBM round-trip deleted)
// ---------------------------------------------------------------------------
__global__ __launch_bounds__(256) void prep_kernel(
    const float* __restrict__ ek,     // [E,D,U]
    short* __restrict__ pb)           // packed B frags: 65536*8 bf16
{
  // frag element (e,ks,ut,lane,j) = ek[e][ks*32+(lane>>4)*8+j][ut*16+(lane&15)]
  int gid = (blockIdx.x << 8) | threadIdx.x;   // [0, 65536)
  int lane = gid & 63, ut = (gid >> 6) & 15, ks = (gid >> 10) & 3, e = gid >> 12;
  int krow = ks * 32 + ((lane >> 4) * 8);
  int ucol = ut * 16 + (lane & 15);
  const float* src = ek + (size_t)(e * 128 + krow) * 256 + ucol;
  short8v v;
#pragma unroll
  for (int j = 0; j < 8; ++j) v[j] = f2bf(src[(size_t)j * 256]);
  *(short8v*)(pb + (size_t)gid * 8) = v;
}

// ---------------------------------------------------------------------------
// main kernel v3: 256 blocks x 1024 threads (16 waves), 32 b-rows per block.
// - waves 0-13 stage the A tile (x fp32 -> bf16 LDS, nt loads);
//   waves 14-15 concurrently compute the gating softmax/top-k for the
//   block's 32 rows directly into wsh (kills prep's latency-bound gating
//   kernel and the wd HBM round-trip).
// - compute: 16 waves = 2 btile x 4 utq x 2 t-halves, occupancy 2x of v2.
// - ALL output stores are PLAIN (not nontemporal): v2's nt stores measured
//   2.24x write inflation (376 MB vs 168 logical) + ~86 MB unexplained fetch
//   -> theory: nt bypasses L2 write-combining, sub-line writes RMW at the
//   memory side. Plain stores aggregate in L2 and evict full dirty lines.
//   x loads stay nt (no-allocate) so the streaming read doesn't evict pb.
// - stg layout [e-chunk][col]: conflict-free LDS writes AND reads, no XOR.
// ---------------------------------------------------------------------------
#define APITCH 2056  // shorts per A row: 2048 + 8 pad
#define WPITCH 64    // floats per wd row (combine reads are 16-lane broadcast)

__global__ __launch_bounds__(1024, 4) void moe_kernel(
    const float* __restrict__ x,     // [B, E*D]
    const float* __restrict__ feat,  // [B, F]
    const float* __restrict__ gk,    // [G, F, E]
    const float* __restrict__ gbias, // [G, E]
    const float* __restrict__ gw,    // [E]
    const float* __restrict__ eb,    // [E, U]
    const short* __restrict__ pb,    // packed bf16 B frags
    float* __restrict__ out)         // concat [B,G*U] then eo [B,U,E]
{
  __shared__ __align__(16) short ash[32 * APITCH];  // 131584 B
  __shared__ __align__(16) float wsh[32 * WPITCH];  // 8192 B
  __shared__ __align__(16) float stg[16 * 256];     // 16384 B (1KB per wave)
  int bt = blockIdx.x, tid = threadIdx.x;
  int w = tid >> 6, lane = tid & 63;

  if (w < 14) {
    // ---- A-tile staging: 32 rows x 2048 fp32 -> bf16 LDS, nt float4 reads
    const float4v* s = (const float4v*)(x + (size_t)bt * 32 * 2048);
    for (int idx = w * 64 + lane; idx < 16384; idx += 896) {
      int row = idx >> 9;            // / 512 f4-per-row
      int colf = (idx & 511) << 2;
      float4v v = __builtin_nontemporal_load(s + idx);
      short4v sv;
      sv[0] = f2bf(v[0]); sv[1] = f2bf(v[1]); sv[2] = f2bf(v[2]); sv[3] = f2bf(v[3]);
      *(short4v*)&ash[row * APITCH + colf] = sv;
    }
  } else {
    // ---- gating for 16 of the block's 32 rows (wave 14: rows 0-15, 15: 16-31)
    int rb = (w - 14) * 16;
    int gate = lane >> 4, e = lane & 15;   // lane = (gate, expert)
    float gwv = gw[e];
    float bias = gbias[gate * 16 + e];
    const float* gkp = gk + (size_t)gate * (NF * NE) + e;
#pragma unroll 1
    for (int p = 0; p < 2; ++p) {
      float acc[8];
#pragma unroll
      for (int i = 0; i < 8; ++i) acc[i] = bias;
      const float* fb = feat + ((size_t)bt * 32 + rb + p * 8) * 256;
      for (int f = 0; f < NF; f += 4) {
        float g0 = gkp[(f + 0) * 16], g1 = gkp[(f + 1) * 16];
        float g2 = gkp[(f + 2) * 16], g3 = gkp[(f + 3) * 16];
#pragma unroll
        for (int i = 0; i < 8; ++i) {      // feat read is wave-uniform (broadcast)
          float4v fv = *(const float4v*)(fb + i * 256 + f);
          acc[i] = fmaf(fv[0], g0, acc[i]);
          acc[i] = fmaf(fv[1], g1, acc[i]);
          acc[i] = fmaf(fv[2], g2, acc[i]);
          acc[i] = fmaf(fv[3], g3, acc[i]);
        }
      }
#pragma unroll 1
      for (int i = 0; i < 8; ++i) {
        float v = acc[i] > 0.f ? acc[i] : 0.f;  // relu
        v *= gwv;                               // * global_weights
        // sharp softmax over 16 experts (within 16-lane group)
        float m = v;
#pragma unroll
        for (int off = 1; off < 16; off <<= 1) m = fmaxf(m, __shfl_xor(m, off, 16));
        float ex = exp2f((v - m) * ITEMP_LOG2E);
        float s = ex;
#pragma unroll
        for (int off = 1; off < 16; off <<= 1) s += __shfl_xor(s, off, 16);
        float pr = ex / s;
        // iterative top-6 (max value, min-index tie-break = jax top_k order)
        float cur = pr;
        float topv[NK]; int topi[NK];
#pragma unroll
        for (int r = 0; r < NK; ++r) {
          float mv = cur;
#pragma unroll
          for (int off = 1; off < 16; off <<= 1) mv = fmaxf(mv, __shfl_xor(mv, off, 16));
          int cand = (cur == mv) ? e : 16;
#pragma unroll
          for (int off = 1; off < 16; off <<= 1) cand = min(cand, __shfl_xor(cand, off, 16));
          topv[r] = mv; topi[r] = cand;
          if (e == cand) cur = -1.f;
        }
        // second sharp softmax over the 6 selected (topv[0] is the max)
        float wv[NK], wsum = 0.f;
#pragma unroll
        for (int r = 0; r < NK; ++r) {
          wv[r] = exp2f((topv[r] - topv[0]) * ITEMP_LOG2E);
          wsum += wv[r];
        }
        float inv = 1.f / wsum;
        float wdv = 0.f;
#pragma unroll
        for (int r = 0; r < NK; ++r) wdv = (topi[r] == e) ? wv[r] * inv : wdv;
        wsh[(rb + p * 8 + i) * WPITCH + lane] = wdv;  // gate*16+e == lane
      }
    }
  }
  __syncthreads();

  // ---- compute: 16 waves = 2 btile x 4 utq x 2 th; each wave 2 u-tiles
  int btile = w >> 3, utq = (w >> 1) & 3, th = w & 1;
  int q = lane >> 4, col = lane & 15;   // C/D frag: row=q*4+r, col=lane&15
  int am = lane & 15;                   // A frag: m = lane&15
  float* outcat = out;
  float* outeo = out + (size_t)NB * NG * NU;
  const short8v* pbv = (const short8v*)pb;
  float* ws = stg + w * 256;            // this wave's 1KB staging slice
  size_t bb = (size_t)bt * 32 + btile * 16;
  int arow = (btile * 16 + am) * APITCH;
  int wrow = (btile * 16 + q * 4) * WPITCH;

  float csave[4][4];                    // concat values from tl=0, flushed at tl=1

#pragma unroll 1
  for (int tl = 0; tl < 2; ++tl) {
    int t = th * 2 + tl;
    int ut = utq * 4 + t;               // this wave's u-tile
    float4v acc[16];
    float4v zero = {0.f, 0.f, 0.f, 0.f};
#pragma unroll
    for (int e = 0; e < 16; ++e) acc[e] = zero;
#pragma unroll
    for (int e = 0; e < 16; ++e) {
#pragma unroll
      for (int ks = 0; ks < 4; ++ks) {
        short8v a = *(const short8v*)&ash[arow + e * 128 + ks * 32 + q * 8];
        short8v b = pbv[((e * 4 + ks) * 16 + ut) * 64 + lane];
        acc[e] = __builtin_amdgcn_mfma_f32_16x16x32_bf16(a, b, acc[e], 0, 0, 0);
      }
    }
    // bias + leaky_relu
    float v[16][4];
#pragma unroll
    for (int e = 0; e < 16; ++e) {
      float bv = eb[e * 256 + ut * 16 + col];
#pragma unroll
      for (int r = 0; r < 4; ++r) {
        float z = acc[e][r] + bv;
        v[e][r] = z > 0.f ? z : 0.2f * z;
      }
    }
    // eo writes via per-wave LDS transpose: 4 rounds (one q each) per r.
    // staging layout [c][col]: write slot = c*16+col (16 consecutive float4
    // per instruction -> conflict-free), read slot = lane (linear).
    // Each flush covers one contiguous 1KB (b,ut) region [16 u][16 e].
#pragma unroll
    for (int r = 0; r < 4; ++r) {
#pragma unroll
      for (int qq = 0; qq < 4; ++qq) {
        if (q == qq) {
#pragma unroll
          for (int c = 0; c < 4; ++c) {
            float4v o = {v[4 * c + 0][r], v[4 * c + 1][r], v[4 * c + 2][r], v[4 * c + 3][r]};
            *(float4v*)(ws + (c * 16 + col) * 4) = o;
          }
        }
        __builtin_amdgcn_wave_barrier();   // fence: write -> read (wave-synchronous LDS)
        {
          size_t b = bb + (size_t)(qq * 4 + r);
          float4v val = *(const float4v*)(ws + lane * 4);  // linear, conflict-free
          // slot lane = (c=lane>>4, col=lane&15) -> u = ut*16+(lane&15), e = 4*(lane>>4)
          float* dst = outeo + b * 4096 + (size_t)ut * 256 + (lane & 15) * 16 + (lane >> 4) * 4;
          *(float4v*)dst = val;            // plain store: full dirty lines via L2
        }
        __builtin_amdgcn_wave_barrier();   // fence: read -> next round's write
      }
    }
    // dense combine: out[b,g,u] = sum_e wd[b,g,e] * eo[b,u,e]
    // pair stores across (tl=0, tl=1): adjacent 64B halves of one 128B line.
#pragma unroll
    for (int r = 0; r < 4; ++r) {
      size_t b = bb + (size_t)(q * 4 + r);
#pragma unroll
      for (int g = 0; g < 4; ++g) {
        float sacc = 0.f;
#pragma unroll
        for (int ec = 0; ec < 16; ec += 4) {
          float4v wv = *(const float4v*)&wsh[wrow + r * WPITCH + g * 16 + ec];
          sacc = fmaf(wv[0], v[ec][r], sacc);
          sacc = fmaf(wv[1], v[ec + 1][r], sacc);
          sacc = fmaf(wv[2], v[ec + 2][r], sacc);
          sacc = fmaf(wv[3], v[ec + 3][r], sacc);
        }
        if (tl == 0) {
          csave[r][g] = sacc;
        } else {
          float* cb = outcat + b * 1024 + g * 256 + (ut - 1) * 16 + col;
          cb[0] = csave[r][g];
          cb[16] = sacc;
        }
      }
    }
  }
}

extern "C" void kernel_launch(void* const* d_in, const int* in_sizes, int n_in,
                              void* d_out, int out_size, void* d_ws, size_t ws_size,
                              hipStream_t stream) {
  const float* x     = (const float*)d_in[0];  // [B, E*D]
  const float* feat  = (const float*)d_in[1];  // [B, F]
  const float* ek    = (const float*)d_in[2];  // [E, D, U]
  const float* eb    = (const float*)d_in[3];  // [E, U]
  const float* gk    = (const float*)d_in[4];  // [G, F, E]
  const float* gbias = (const float*)d_in[5];  // [G, E]
  const float* gw    = (const float*)d_in[6];  // [E]
  float* out = (float*)d_out;
  short* pbf = (short*)d_ws;                   // 1MB packed bf16 B frags

  prep_kernel<<<256, 256, 0, stream>>>(ek, pbf);
  moe_kernel<<<256, 1024, 0, stream>>>(x, feat, gk, gbias, gw, eb, pbf, out);
}